// Round 1
// baseline (2191.260 us; speedup 1.0000x reference)
//
#include <hip/hip_runtime.h>
#include <hip/hip_bf16.h>
#include <math.h>

// Problem constants (match reference)
#define B_ 2
#define T_ 2048
#define E_ 1024
#define H_ 16
#define D_ 64
// scale = D^-0.5 = 0.125 exactly

// ---------------------------------------------------------------------------
// Kernel 1: fused per-head QKV projection.
// grid (T/64, H, B), block 256. Each block computes a 64(t) x 64(d) tile of
// q,k,v for one head, looping E in chunks of 32 through LDS.
// ---------------------------------------------------------------------------
__global__ __launch_bounds__(256) void proj_kernel(
    const float* __restrict__ in,
    const float* __restrict__ kw, const float* __restrict__ kb,
    const float* __restrict__ qw, const float* __restrict__ qb,
    const float* __restrict__ vw, const float* __restrict__ vb,
    float* __restrict__ qo, float* __restrict__ ko, float* __restrict__ vo)
{
  __shared__ __align__(16) float in_s[64][36];     // [t][e], pad to 36 for aligned float4 stores
  __shared__ __align__(16) float w_s[3][32][64];   // [tensor][e][d]
  const int tid  = threadIdx.x;
  const int lane = tid & 63;   // d
  const int tg   = tid >> 6;   // t-group 0..3
  const int t0   = blockIdx.x * 64;
  const int h    = blockIdx.y;
  const int b    = blockIdx.z;

  float aq[16], ak[16], av[16];
  #pragma unroll
  for (int i = 0; i < 16; ++i) { aq[i] = 0.f; ak[i] = 0.f; av[i] = 0.f; }

  const float* wptr[3] = { qw, kw, vw };

  for (int e0 = 0; e0 < E_; e0 += 32) {
    __syncthreads();
    // load input tile: 64 t x 32 e
    {
      const int ec = (tid & 7) * 4;
      const int tl = tid >> 3;           // 0..31
      #pragma unroll
      for (int p = 0; p < 2; ++p) {
        const int t = tl + p * 32;
        float4 val = *(const float4*)(in + ((size_t)(b * T_ + t0 + t)) * E_ + e0 + ec);
        *(float4*)&in_s[t][ec] = val;
      }
    }
    // load 3 weight tiles: 32 e x 64 d each
    {
      const int dc = (tid & 15) * 4;
      const int el = tid >> 4;           // 0..15
      #pragma unroll
      for (int x = 0; x < 3; ++x) {
        const float* w = wptr[x];
        #pragma unroll
        for (int p = 0; p < 2; ++p) {
          const int e = el + p * 16;
          float4 val = *(const float4*)(w + ((size_t)h * E_ + e0 + e) * D_ + dc);
          *(float4*)&w_s[x][e][dc] = val;
        }
      }
    }
    __syncthreads();
    #pragma unroll 4
    for (int e = 0; e < 32; ++e) {
      const float wq = w_s[0][e][lane];
      const float wk = w_s[1][e][lane];
      const float wv = w_s[2][e][lane];
      #pragma unroll
      for (int i = 0; i < 16; ++i) {
        const float iv = in_s[tg * 16 + i][e];   // wave-uniform -> LDS broadcast
        aq[i] = fmaf(iv, wq, aq[i]);
        ak[i] = fmaf(iv, wk, ak[i]);
        av[i] = fmaf(iv, wv, av[i]);
      }
    }
  }
  const float bq = qb[h * D_ + lane];
  const float bk = kb[h * D_ + lane];
  const float bv = vb[h * D_ + lane];
  const size_t base = ((size_t)(b * H_ + h) * T_ + t0 + tg * 16) * D_ + lane;
  #pragma unroll
  for (int i = 0; i < 16; ++i) {
    const size_t idx = base + (size_t)i * D_;
    qo[idx] = aq[i] + bq;
    ko[idx] = ak[i] + bk;
    vo[idx] = av[i] + bv;
  }
}

// Load a 64x64 fp32 tile (row stride D_=64, contiguous) into LDS [64][65].
__device__ __forceinline__ void load_tile64(const float* __restrict__ src, size_t row0,
                                            float (*dst)[65], int tid)
{
  const int c4 = (tid & 15) * 4;
  const int rb = tid >> 4;   // 0..15
  #pragma unroll
  for (int p = 0; p < 4; ++p) {
    const int r = rb + p * 16;
    float4 val = *(const float4*)(src + (row0 + r) * D_ + c4);
    dst[r][c4 + 0] = val.x; dst[r][c4 + 1] = val.y;
    dst[r][c4 + 2] = val.z; dst[r][c4 + 3] = val.w;
  }
}

// ---------------------------------------------------------------------------
// Kernel 2: per-COLUMN softmax stats (softmax is over the query axis!).
// grid (T/64 s-tiles, H, B), block 256. Block owns 64 columns s; iterates
// t-tiles >= s-tile with online max/expsum per column strip, then reduces
// the 4 thread-group strips.
// ---------------------------------------------------------------------------
__global__ __launch_bounds__(256) void stats_kernel(
    const float* __restrict__ q, const float* __restrict__ k,
    float* __restrict__ mo, float* __restrict__ lo)
{
  __shared__ float k_s[64][65];   // [s][d]
  __shared__ float q_s[64][65];   // [t][d]
  __shared__ float red_m[4][64];
  __shared__ float red_l[4][64];
  const int tid  = threadIdx.x;
  const int lane = tid & 63;   // s (local)
  const int tg   = tid >> 6;
  const int js   = blockIdx.x;
  const int bh   = blockIdx.z * H_ + blockIdx.y;
  const int s0   = js * 64;
  const int sg   = s0 + lane;  // global column

  load_tile64(k, (size_t)bh * T_ + s0, k_s, tid);

  float m = -INFINITY, l = 0.f;

  for (int tt = js; tt < T_ / 64; ++tt) {
    const int t0 = tt * 64;
    __syncthreads();
    load_tile64(q, (size_t)bh * T_ + t0, q_s, tid);
    __syncthreads();
    float sc[16];
    #pragma unroll
    for (int i = 0; i < 16; ++i) sc[i] = 0.f;
    for (int d = 0; d < 64; ++d) {
      const float kv = k_s[lane][d];          // stride 65 -> conflict-free
      #pragma unroll
      for (int i = 0; i < 16; ++i)
        sc[i] = fmaf(q_s[tg * 16 + i][d], kv, sc[i]);  // broadcast read
    }
    float vals[16];
    float mloc = -INFINITY;
    #pragma unroll
    for (int i = 0; i < 16; ++i) {
      const int t = t0 + tg * 16 + i;
      const float x = sc[i] * 0.125f;
      const bool valid = (t >= sg);           // causal: keep s <= t
      vals[i] = valid ? x : -INFINITY;
      if (valid) mloc = fmaxf(mloc, x);
    }
    if (mloc > m) { l *= __expf(m - mloc); m = mloc; }  // m=-inf -> exp(-inf)=0
    if (m != -INFINITY) {
      #pragma unroll
      for (int i = 0; i < 16; ++i)
        l += __expf(vals[i] - m);             // vals=-inf -> 0
    }
  }
  red_m[tg][lane] = m; red_l[tg][lane] = l;
  __syncthreads();
  if (tid < 64) {
    float M = red_m[0][tid];
    #pragma unroll
    for (int g = 1; g < 4; ++g) M = fmaxf(M, red_m[g][tid]);
    float L = 0.f;
    #pragma unroll
    for (int g = 0; g < 4; ++g) L += red_l[g][tid] * __expf(red_m[g][tid] - M);
    mo[(size_t)bh * T_ + s0 + tid] = M;
    lo[(size_t)bh * T_ + s0 + tid] = L;
  }
}

// ---------------------------------------------------------------------------
// Kernel 3: output. grid (T/64 t-tiles, H, B), block 256. Recomputes score
// tiles for s-tiles <= t-tile, normalizes with column stats, P through LDS
// (thread-layout switch), accumulates P @ V, writes (B,T,H*D).
// ---------------------------------------------------------------------------
__global__ __launch_bounds__(256) void out_kernel(
    const float* __restrict__ q, const float* __restrict__ k, const float* __restrict__ v,
    const float* __restrict__ mo, const float* __restrict__ lo,
    float* __restrict__ out)
{
  __shared__ float q_s[64][65];    // [t][d]
  __shared__ float kv_s[64][65];   // k tile then v tile
  __shared__ float p_s[64][65];    // [t][s]
  __shared__ float ms_sh[64], ls_sh[64];
  const int tid  = threadIdx.x;
  const int lane = tid & 63;   // s in phase 1, d in phase 2
  const int tg   = tid >> 6;
  const int jt   = blockIdx.x;
  const int bh   = blockIdx.z * H_ + blockIdx.y;
  const int t0   = jt * 64;

  load_tile64(q, (size_t)bh * T_ + t0, q_s, tid);

  float acc[16];
  #pragma unroll
  for (int i = 0; i < 16; ++i) acc[i] = 0.f;

  for (int st = 0; st <= jt; ++st) {
    const int s0 = st * 64;
    __syncthreads();                                  // prev iter done with kv_s/p_s
    load_tile64(k, (size_t)bh * T_ + s0, kv_s, tid);
    if (tid < 64) {
      ms_sh[tid] = mo[(size_t)bh * T_ + s0 + tid];
      ls_sh[tid] = lo[(size_t)bh * T_ + s0 + tid];
    }
    __syncthreads();
    // phase 1: S tile, thread = (tg, s)
    float sc[16];
    #pragma unroll
    for (int i = 0; i < 16; ++i) sc[i] = 0.f;
    for (int d = 0; d < 64; ++d) {
      const float kv = kv_s[lane][d];
      #pragma unroll
      for (int i = 0; i < 16; ++i)
        sc[i] = fmaf(q_s[tg * 16 + i][d], kv, sc[i]);
    }
    const float mcol = ms_sh[lane];
    const float rcol = 1.f / ls_sh[lane];
    const int sg = s0 + lane;
    #pragma unroll
    for (int i = 0; i < 16; ++i) {
      const int t = t0 + tg * 16 + i;
      const float p = (t >= sg) ? __expf(sc[i] * 0.125f - mcol) * rcol : 0.f;
      p_s[tg * 16 + i][lane] = p;
    }
    __syncthreads();                                  // p_s visible, kv_s reads done
    load_tile64(v, (size_t)bh * T_ + s0, kv_s, tid);
    __syncthreads();
    // phase 2: acc += P @ V, thread = (tg, d)
    for (int s = 0; s < 64; ++s) {
      const float vv = kv_s[s][lane];
      #pragma unroll
      for (int i = 0; i < 16; ++i)
        acc[i] = fmaf(p_s[tg * 16 + i][s], vv, acc[i]);  // broadcast read
    }
  }
  // output layout (B, T, H*D), head-major concat
  #pragma unroll
  for (int i = 0; i < 16; ++i) {
    const int t = t0 + tg * 16 + i;
    out[((size_t)(blockIdx.z * T_ + t)) * (H_ * D_) + blockIdx.y * D_ + lane] = acc[i];
  }
}

extern "C" void kernel_launch(void* const* d_in, const int* in_sizes, int n_in,
                              void* d_out, int out_size, void* d_ws, size_t ws_size,
                              hipStream_t stream) {
  const float* in = (const float*)d_in[0];
  const float* kw = (const float*)d_in[1];
  const float* kb = (const float*)d_in[2];
  const float* qw = (const float*)d_in[3];
  const float* qb = (const float*)d_in[4];
  const float* vw = (const float*)d_in[5];
  const float* vb = (const float*)d_in[6];
  float* out = (float*)d_out;

  // workspace layout (fp32): q | k | v | m | l  -> ~50.9 MB total
  float* ws = (float*)d_ws;
  const size_t qkv = (size_t)B_ * H_ * T_ * D_;   // 4,194,304
  float* q  = ws;
  float* k  = q + qkv;
  float* v  = k + qkv;
  float* mo = v + qkv;
  float* lo = mo + (size_t)B_ * H_ * T_;

  dim3 grid(T_ / 64, H_, B_), block(256);
  proj_kernel <<<grid, block, 0, stream>>>(in, kw, kb, qw, qb, vw, vb, q, k, v);
  stats_kernel<<<grid, block, 0, stream>>>(q, k, mo, lo);
  out_kernel  <<<grid, block, 0, stream>>>(q, k, v, mo, lo, out);
}

// Round 2
// 312.732 us; speedup vs baseline: 7.0068x; 7.0068x over previous
//
#include <hip/hip_runtime.h>
#include <hip/hip_bf16.h>
#include <math.h>

#define B_ 2
#define T_ 2048
#define E_ 1024
#define H_ 16
#define D_ 64
#define NT_ (T_/64)   // 32 tiles of 64

typedef __attribute__((ext_vector_type(8))) short bf16x8;   // 8 bf16 = 4 VGPRs (MFMA A/B frag)
typedef __attribute__((ext_vector_type(4))) float f32x4;    // MFMA C/D frag

__device__ __forceinline__ unsigned short f2bf(float x) {   // RNE fp32->bf16
  union { float f; unsigned u; } v; v.f = x;
  unsigned r = v.u + 0x7FFFu + ((v.u >> 16) & 1u);
  return (unsigned short)(r >> 16);
}

// ---------------------------------------------------------------------------
// Kernel 0: weight pack. (H,E,D) fp32 -> (H,D,E) bf16 so MFMA B-fragments
// (8 consecutive e at fixed d) become contiguous ds_read_b128.
// grid (E/64, H, 3), block 256.
// ---------------------------------------------------------------------------
__global__ __launch_bounds__(256) void wpack_kernel(
    const float* __restrict__ qw, const float* __restrict__ kw, const float* __restrict__ vw,
    unsigned short* __restrict__ qwt, unsigned short* __restrict__ kwt, unsigned short* __restrict__ vwt)
{
  __shared__ float s[64][65];
  const int tid = threadIdx.x;
  const int e0 = blockIdx.x * 64;
  const int h  = blockIdx.y;
  const int z  = blockIdx.z;
  const float* w = (z == 0) ? qw : (z == 1) ? kw : vw;
  unsigned short* o = (z == 0) ? qwt : (z == 1) ? kwt : vwt;

  { // load 64(e) x 64(d) fp32 tile, coalesced along d
    const int r = tid >> 2;
    #pragma unroll
    for (int p = 0; p < 4; ++p) {
      const int c = ((tid & 3) * 4 + p * 16);
      float4 f = *(const float4*)(w + ((size_t)(h * E_ + e0 + r)) * D_ + c);
      s[r][c] = f.x; s[r][c+1] = f.y; s[r][c+2] = f.z; s[r][c+3] = f.w;
    }
  }
  __syncthreads();
  { // write transposed: row d, contiguous e, bf16
    const int d  = tid >> 2;
    const int ec = (tid & 3) * 16;
    unsigned short tmp[16];
    #pragma unroll
    for (int j = 0; j < 16; ++j) tmp[j] = f2bf(s[ec + j][d]);
    unsigned short* dst = o + ((size_t)(h * D_ + d)) * E_ + e0 + ec;
    *(bf16x8*)(dst)     = *(const bf16x8*)&tmp[0];
    *(bf16x8*)(dst + 8) = *(const bf16x8*)&tmp[8];
  }
}

// stage a 64x64 bf16 tile (row-major, stride 64) global -> LDS [64][72]
__device__ __forceinline__ void stage_tile(const unsigned short* __restrict__ g,
                                           unsigned short (*dst)[72], int tid)
{
  const int r = tid >> 2;
  const int c = (tid & 3) * 16;
  const unsigned short* src = g + (size_t)r * 64 + c;
  bf16x8 v0 = *(const bf16x8*)(src);
  bf16x8 v1 = *(const bf16x8*)(src + 8);
  *(bf16x8*)&dst[r][c]     = v0;
  *(bf16x8*)&dst[r][c + 8] = v1;
}

// stage a 64x64 bf16 tile TRANSPOSED into LDS: dst[d][s] = g[s][d]
__device__ __forceinline__ void stage_tile_T(const unsigned short* __restrict__ g,
                                             unsigned short (*dst)[72], int tid)
{
  const int sI = tid >> 2;
  const int dc = (tid & 3) * 16;
  const unsigned short* src = g + (size_t)sI * 64 + dc;
  bf16x8 v0 = *(const bf16x8*)(src);
  bf16x8 v1 = *(const bf16x8*)(src + 8);
  #pragma unroll
  for (int j = 0; j < 8; ++j) dst[dc + j][sI] = (unsigned short)v0[j];
  #pragma unroll
  for (int j = 0; j < 8; ++j) dst[dc + 8 + j][sI] = (unsigned short)v1[j];
}

// ---------------------------------------------------------------------------
// Kernel 1: fused QKV projection, MFMA. grid (T/64, H, B), block 256 (4 waves).
// Block computes 64(t) x 64(d) for q,k,v of one head. K-loop over E in 64-chunks.
// ---------------------------------------------------------------------------
__global__ __launch_bounds__(256) void proj_kernel(
    const float* __restrict__ in,
    const unsigned short* __restrict__ qwt, const unsigned short* __restrict__ kwt,
    const unsigned short* __restrict__ vwt,
    const float* __restrict__ qb, const float* __restrict__ kb, const float* __restrict__ vb,
    unsigned short* __restrict__ qo, unsigned short* __restrict__ ko, unsigned short* __restrict__ vo)
{
  __shared__ __align__(16) unsigned short in_s[64][72];
  __shared__ __align__(16) unsigned short w_s[3][64][72];
  const int tid  = threadIdx.x;
  const int lane = tid & 63, wv = tid >> 6;
  const int l15  = lane & 15, quad = lane >> 4;
  const int t0 = blockIdx.x * 64, h = blockIdx.y, b = blockIdx.z;

  f32x4 acc[3][4];
  #pragma unroll
  for (int x = 0; x < 3; ++x)
    #pragma unroll
    for (int nb = 0; nb < 4; ++nb) acc[x][nb] = (f32x4){0.f, 0.f, 0.f, 0.f};

  for (int e0 = 0; e0 < E_; e0 += 64) {
    __syncthreads();
    { // input tile 64(t) x 64(e): fp32 -> bf16
      const int r = tid >> 2;
      const float* src = in + ((size_t)(b * T_ + t0 + r)) * E_ + e0;
      #pragma unroll
      for (int p = 0; p < 4; ++p) {
        const int c = (tid & 3) * 16 + p * 4;
        float4 f = *(const float4*)(src + c);
        unsigned short u[4] = { f2bf(f.x), f2bf(f.y), f2bf(f.z), f2bf(f.w) };
        *(ushort4*)&in_s[r][c] = *(const ushort4*)u;
      }
    }
    { // weight tiles 64(d) x 64(e), already bf16+transposed
      const int d = tid >> 2;
      const int c = (tid & 3) * 16;
      const size_t off = ((size_t)(h * D_ + d)) * E_ + e0 + c;
      const unsigned short* srcs[3] = { qwt + off, kwt + off, vwt + off };
      #pragma unroll
      for (int x = 0; x < 3; ++x) {
        bf16x8 v0 = *(const bf16x8*)(srcs[x]);
        bf16x8 v1 = *(const bf16x8*)(srcs[x] + 8);
        *(bf16x8*)&w_s[x][d][c]     = v0;
        *(bf16x8*)&w_s[x][d][c + 8] = v1;
      }
    }
    __syncthreads();
    #pragma unroll
    for (int kk = 0; kk < 64; kk += 32) {
      bf16x8 a = *(const bf16x8*)&in_s[wv * 16 + l15][kk + quad * 8];
      #pragma unroll
      for (int x = 0; x < 3; ++x)
        #pragma unroll
        for (int nb = 0; nb < 4; ++nb) {
          bf16x8 bf = *(const bf16x8*)&w_s[x][nb * 16 + l15][kk + quad * 8];
          acc[x][nb] = __builtin_amdgcn_mfma_f32_16x16x32_bf16(a, bf, acc[x][nb], 0, 0, 0);
        }
    }
  }
  // epilogue: + bias, bf16 store to (bh, t, d)
  const size_t obase = (size_t)(b * H_ + h) * T_;
  #pragma unroll
  for (int x = 0; x < 3; ++x) {
    const float* bias = (x == 0) ? qb : (x == 1) ? kb : vb;
    unsigned short* outp = (x == 0) ? qo : (x == 1) ? ko : vo;
    #pragma unroll
    for (int nb = 0; nb < 4; ++nb) {
      const int d = nb * 16 + l15;
      const float bvv = bias[h * D_ + d];
      #pragma unroll
      for (int r = 0; r < 4; ++r) {
        const int t = t0 + wv * 16 + quad * 4 + r;
        outp[(obase + t) * D_ + d] = f2bf(acc[x][nb][r] + bvv);
      }
    }
  }
}

// ---------------------------------------------------------------------------
// Kernel 2: column softmax denominators (softmax over QUERY axis).
// grid (T/64 s-tiles, H, B), block 256. No max subtraction: |S*scale| <~ 2,
// exp is safe in fp32. Writes rl = 1/sum.
// ---------------------------------------------------------------------------
__global__ __launch_bounds__(256) void stats_kernel(
    const unsigned short* __restrict__ q, const unsigned short* __restrict__ k,
    float* __restrict__ rl)
{
  __shared__ __align__(16) unsigned short k_s[64][72];
  __shared__ __align__(16) unsigned short q_s[64][72];
  __shared__ float red[4][64];
  const int tid  = threadIdx.x;
  const int lane = tid & 63, wv = tid >> 6;
  const int l15  = lane & 15, quad = lane >> 4;
  const int js = blockIdx.x, bh = blockIdx.z * H_ + blockIdx.y;
  const int s0 = js * 64;

  stage_tile(k + (size_t)(bh * T_ + s0) * 64, k_s, tid);

  float lsum[4] = {0.f, 0.f, 0.f, 0.f};

  for (int tt = js; tt < NT_; ++tt) {
    const int t0 = tt * 64;
    __syncthreads();
    stage_tile(q + (size_t)(bh * T_ + t0) * 64, q_s, tid);
    __syncthreads();
    f32x4 sacc[4];
    #pragma unroll
    for (int sb = 0; sb < 4; ++sb) sacc[sb] = (f32x4){0.f, 0.f, 0.f, 0.f};
    #pragma unroll
    for (int kk = 0; kk < 64; kk += 32) {
      bf16x8 a = *(const bf16x8*)&q_s[wv * 16 + l15][kk + quad * 8];
      #pragma unroll
      for (int sb = 0; sb < 4; ++sb) {
        bf16x8 bf = *(const bf16x8*)&k_s[sb * 16 + l15][kk + quad * 8];
        sacc[sb] = __builtin_amdgcn_mfma_f32_16x16x32_bf16(a, bf, sacc[sb], 0, 0, 0);
      }
    }
    #pragma unroll
    for (int sb = 0; sb < 4; ++sb) {
      const int sg = s0 + sb * 16 + l15;
      #pragma unroll
      for (int r = 0; r < 4; ++r) {
        const int tg = t0 + wv * 16 + quad * 4 + r;
        if (tg >= sg) lsum[sb] += __expf(sacc[sb][r] * 0.125f);
      }
    }
  }
  #pragma unroll
  for (int sb = 0; sb < 4; ++sb) {
    lsum[sb] += __shfl_xor(lsum[sb], 16);
    lsum[sb] += __shfl_xor(lsum[sb], 32);
  }
  if (lane < 16) {
    #pragma unroll
    for (int sb = 0; sb < 4; ++sb) red[wv][sb * 16 + lane] = lsum[sb];
  }
  __syncthreads();
  if (tid < 64) {
    const float l = red[0][tid] + red[1][tid] + red[2][tid] + red[3][tid];
    rl[(size_t)bh * T_ + s0 + tid] = 1.0f / l;
  }
}

// ---------------------------------------------------------------------------
// Kernel 3: output. grid (T/64 t-tiles, H, B), block 256.
// Recompute S (identical MFMAs as stats), U = exp(S*scale)*rl masked,
// LDS round-trip to A-layout, MFMA U @ V (V transposed during staging).
// ---------------------------------------------------------------------------
__global__ __launch_bounds__(256) void out_kernel(
    const unsigned short* __restrict__ q, const unsigned short* __restrict__ k,
    const unsigned short* __restrict__ v, const float* __restrict__ rl,
    float* __restrict__ out)
{
  __shared__ __align__(16) unsigned short q_s[64][72];
  __shared__ __align__(16) unsigned short k_s[64][72];
  __shared__ __align__(16) unsigned short vt_s[64][72];  // [d][s]
  __shared__ __align__(16) unsigned short u_s[64][72];   // [t][s] bf16
  __shared__ float rl_sh[64];
  const int tid  = threadIdx.x;
  const int lane = tid & 63, wv = tid >> 6;
  const int l15  = lane & 15, quad = lane >> 4;
  const int jt = blockIdx.x, bh = blockIdx.z * H_ + blockIdx.y;
  const int t0 = jt * 64;

  stage_tile(q + (size_t)(bh * T_ + t0) * 64, q_s, tid);

  f32x4 oacc[4];
  #pragma unroll
  for (int nb = 0; nb < 4; ++nb) oacc[nb] = (f32x4){0.f, 0.f, 0.f, 0.f};

  for (int st = 0; st <= jt; ++st) {
    const int s0 = st * 64;
    __syncthreads();   // prev-iter k_s/vt_s/u_s reads done; q_s visible (iter 0)
    stage_tile(k + (size_t)(bh * T_ + s0) * 64, k_s, tid);
    stage_tile_T(v + (size_t)(bh * T_ + s0) * 64, vt_s, tid);
    if (tid < 64) rl_sh[tid] = rl[(size_t)bh * T_ + s0 + tid];
    __syncthreads();
    // S tile via MFMA
    f32x4 sacc[4];
    #pragma unroll
    for (int sb = 0; sb < 4; ++sb) sacc[sb] = (f32x4){0.f, 0.f, 0.f, 0.f};
    #pragma unroll
    for (int kk = 0; kk < 64; kk += 32) {
      bf16x8 a = *(const bf16x8*)&q_s[wv * 16 + l15][kk + quad * 8];
      #pragma unroll
      for (int sb = 0; sb < 4; ++sb) {
        bf16x8 bf = *(const bf16x8*)&k_s[sb * 16 + l15][kk + quad * 8];
        sacc[sb] = __builtin_amdgcn_mfma_f32_16x16x32_bf16(a, bf, sacc[sb], 0, 0, 0);
      }
    }
    // U = exp(S*scale)*rl (masked), store C-layout -> LDS [t][s] bf16
    #pragma unroll
    for (int sb = 0; sb < 4; ++sb) {
      const int sg = s0 + sb * 16 + l15;
      const float rcol = rl_sh[sb * 16 + l15];
      #pragma unroll
      for (int r = 0; r < 4; ++r) {
        const int tg = t0 + wv * 16 + quad * 4 + r;
        const float uv = (tg >= sg) ? __expf(sacc[sb][r] * 0.125f) * rcol : 0.f;
        u_s[wv * 16 + quad * 4 + r][sb * 16 + l15] = f2bf(uv);
      }
    }
    __syncthreads();
    // O += U @ V' : A-frag from u_s rows (own strip), B-frag from vt_s
    #pragma unroll
    for (int kk = 0; kk < 64; kk += 32) {
      bf16x8 a = *(const bf16x8*)&u_s[wv * 16 + l15][kk + quad * 8];
      #pragma unroll
      for (int nb = 0; nb < 4; ++nb) {
        bf16x8 bf = *(const bf16x8*)&vt_s[nb * 16 + l15][kk + quad * 8];
        oacc[nb] = __builtin_amdgcn_mfma_f32_16x16x32_bf16(a, bf, oacc[nb], 0, 0, 0);
      }
    }
  }
  // write (B, T, H*D) fp32
  #pragma unroll
  for (int nb = 0; nb < 4; ++nb) {
    const int d = nb * 16 + l15;
    #pragma unroll
    for (int r = 0; r < 4; ++r) {
      const int t = t0 + wv * 16 + quad * 4 + r;
      out[((size_t)(blockIdx.z * T_ + t)) * (H_ * D_) + blockIdx.y * D_ + d] = oacc[nb][r];
    }
  }
}

extern "C" void kernel_launch(void* const* d_in, const int* in_sizes, int n_in,
                              void* d_out, int out_size, void* d_ws, size_t ws_size,
                              hipStream_t stream) {
  const float* in = (const float*)d_in[0];
  const float* kw = (const float*)d_in[1];
  const float* kb = (const float*)d_in[2];
  const float* qw = (const float*)d_in[3];
  const float* qb = (const float*)d_in[4];
  const float* vw = (const float*)d_in[5];
  const float* vb = (const float*)d_in[6];
  float* out = (float*)d_out;

  // workspace (bf16 unless noted): qwt|kwt|vwt (H,D,E) | q|k|v (B,H,T,D) | rl fp32
  unsigned short* wsu = (unsigned short*)d_ws;
  const size_t wsz  = (size_t)H_ * D_ * E_;      // 1,048,576
  const size_t qkvz = (size_t)B_ * H_ * T_ * D_; // 4,194,304
  unsigned short* qwt = wsu;
  unsigned short* kwt = qwt + wsz;
  unsigned short* vwt = kwt + wsz;
  unsigned short* qb16 = vwt + wsz;
  unsigned short* kb16 = qb16 + qkvz;
  unsigned short* vb16 = kb16 + qkvz;
  float* rl = (float*)(vb16 + qkvz);

  dim3 blk(256);
  wpack_kernel<<<dim3(E_ / 64, H_, 3), blk, 0, stream>>>(qw, kw, vw, qwt, kwt, vwt);
  proj_kernel <<<dim3(NT_, H_, B_), blk, 0, stream>>>(in, qwt, kwt, vwt, qb, kb, vb,
                                                      qb16, kb16, vb16);
  stats_kernel<<<dim3(NT_, H_, B_), blk, 0, stream>>>(qb16, kb16, rl);
  out_kernel  <<<dim3(NT_, H_, B_), blk, 0, stream>>>(qb16, kb16, vb16, rl, out);
}

// Round 3
// 192.459 us; speedup vs baseline: 11.3856x; 1.6249x over previous
//
#include <hip/hip_runtime.h>
#include <hip/hip_bf16.h>
#include <math.h>

#define B_ 2
#define T_ 2048
#define E_ 1024
#define H_ 16
#define D_ 64
#define NT_ 32          // T/64 tiles

typedef __attribute__((ext_vector_type(8))) short bf16x8;   // MFMA A/B frag (4 VGPRs)
typedef __attribute__((ext_vector_type(4))) float f32x4;    // MFMA C/D frag

__device__ __forceinline__ unsigned short f2bf(float x) {   // RNE fp32->bf16
  union { float f; unsigned u; } v; v.f = x;
  unsigned r = v.u + 0x7FFFu + ((v.u >> 16) & 1u);
  return (unsigned short)(r >> 16);
}
__device__ __forceinline__ float bf2f(unsigned short u) {
  union { float f; unsigned u; } v; v.u = ((unsigned)u) << 16; return v.f;
}
__device__ __forceinline__ unsigned pk2bf(float a, float b) {  // low=a, high=b
  return (unsigned)f2bf(a) | ((unsigned)f2bf(b) << 16);
}

// Async global->LDS: one wave-instr stages 8 rows x 64 bf16 (8 blocks of 16B),
// XOR-swizzled: LDS slot (row, bs) holds global block bs ^ (row&7).
// lptr must be wave-uniform (base of an 8-row group); lane i -> lptr + i*16.
__device__ __forceinline__ void dma8(const unsigned short* g, int gstride,
                                     unsigned short* l, int lane)
{
  const int r = lane >> 3, bg = (lane & 7) ^ (r & 7);
  __builtin_amdgcn_global_load_lds(
      (const __attribute__((address_space(1))) void*)(g + (size_t)r * gstride + bg * 8),
      (__attribute__((address_space(3))) void*)l, 16, 0, 0);
}
// Swizzled b128 frag read from a 64-col tile: logical block g (0..7) of row.
__device__ __forceinline__ bf16x8 frag(const unsigned short* tile, int row, int g) {
  return *(const bf16x8*)(tile + row * 64 + (((g ^ row) & 7) << 3));
}

// ---------------------------------------------------------------------------
// input pre-pack: (B,T,E) fp32 -> bf16 same layout. grid 2048 x 256.
// ---------------------------------------------------------------------------
__global__ __launch_bounds__(256) void inpack_kernel(const float* __restrict__ in,
                                                     unsigned short* __restrict__ o) {
  const size_t i = ((size_t)blockIdx.x * 256 + threadIdx.x) * 8;
  float4 f0 = *(const float4*)(in + i);
  float4 f1 = *(const float4*)(in + i + 4);
  unsigned u[4] = { pk2bf(f0.x, f0.y), pk2bf(f0.z, f0.w),
                    pk2bf(f1.x, f1.y), pk2bf(f1.z, f1.w) };
  *(bf16x8*)(o + i) = *(const bf16x8*)u;
}

// ---------------------------------------------------------------------------
// weight pack: (H,E,D) fp32 -> (H,D,E) bf16. grid (E/64, H, 3) x 256.
// ---------------------------------------------------------------------------
__global__ __launch_bounds__(256) void wpack_kernel(
    const float* __restrict__ qw, const float* __restrict__ kw, const float* __restrict__ vw,
    unsigned short* __restrict__ qwt, unsigned short* __restrict__ kwt,
    unsigned short* __restrict__ vwt)
{
  __shared__ float s[64][65];
  const int tid = threadIdx.x;
  const int e0 = blockIdx.x * 64, h = blockIdx.y, z = blockIdx.z;
  const float* w = (z == 0) ? qw : (z == 1) ? kw : vw;
  unsigned short* o = (z == 0) ? qwt : (z == 1) ? kwt : vwt;
  {
    const int r = tid >> 2;
    #pragma unroll
    for (int p = 0; p < 4; ++p) {
      const int c = (tid & 3) * 4 + p * 16;
      float4 f = *(const float4*)(w + ((size_t)(h * E_ + e0 + r)) * D_ + c);
      s[r][c] = f.x; s[r][c+1] = f.y; s[r][c+2] = f.z; s[r][c+3] = f.w;
    }
  }
  __syncthreads();
  {
    const int d = tid >> 2, ec = (tid & 3) * 16;
    unsigned short tmp[16];
    #pragma unroll
    for (int j = 0; j < 16; ++j) tmp[j] = f2bf(s[ec + j][d]);
    unsigned short* dst = o + ((size_t)(h * D_ + d)) * E_ + e0 + ec;
    *(bf16x8*)(dst)     = *(const bf16x8*)&tmp[0];
    *(bf16x8*)(dst + 8) = *(const bf16x8*)&tmp[8];
  }
}

// ---------------------------------------------------------------------------
// QKV projection. grid (T/128, H, B) = 512 blocks x 256. 128(t)x64(d) per
// block for q,k,v; E-loop chunk 64, fully double-buffered via global_load_lds.
// ---------------------------------------------------------------------------
__global__ __launch_bounds__(256) void proj_kernel(
    const unsigned short* __restrict__ in16,
    const unsigned short* __restrict__ qwt, const unsigned short* __restrict__ kwt,
    const unsigned short* __restrict__ vwt,
    const float* __restrict__ qb, const float* __restrict__ kb, const float* __restrict__ vb,
    unsigned short* __restrict__ qo, unsigned short* __restrict__ ko,
    unsigned short* __restrict__ vo)
{
  __shared__ __align__(16) unsigned short in_s[2][128 * 64];   // 32 KB
  __shared__ __align__(16) unsigned short w_s[2][3][64 * 64];  // 48 KB
  const int tid = threadIdx.x;
  const int lane = tid & 63, wv = tid >> 6;
  const int l15 = lane & 15, quad = lane >> 4;
  const int t0 = blockIdx.x * 128, h = blockIdx.y, b = blockIdx.z;
  const unsigned short* wts[3] = { qwt, kwt, vwt };

  f32x4 acc[3][2][4];
  #pragma unroll
  for (int x = 0; x < 3; ++x)
    #pragma unroll
    for (int s = 0; s < 2; ++s)
      #pragma unroll
      for (int nb = 0; nb < 4; ++nb) acc[x][s][nb] = (f32x4){0.f, 0.f, 0.f, 0.f};

  // stage E-chunk e0 into buffer bi
#define PROJ_STAGE(e0_, bi_)                                                      \
  {                                                                               \
    const unsigned short* gin = in16 + ((size_t)(b * T_ + t0)) * E_ + (e0_);      \
    _Pragma("unroll")                                                             \
    for (int p = 0; p < 4; ++p) {                                                 \
      const int br = wv * 32 + p * 8;                                             \
      dma8(gin + (size_t)br * E_, E_, &in_s[bi_][br * 64], lane);                 \
    }                                                                             \
    _Pragma("unroll")                                                             \
    for (int j = 0; j < 6; ++j) {                                                 \
      const int idx = wv * 6 + j;                                                 \
      const int x = idx >> 3, br = (idx & 7) * 8;                                 \
      dma8(wts[x] + ((size_t)(h * D_ + br)) * E_ + (e0_), E_,                     \
           &w_s[bi_][x][br * 64], lane);                                          \
    }                                                                             \
  }

  PROJ_STAGE(0, 0);
  __syncthreads();
  for (int e = 0; e < 16; ++e) {
    const int bi = e & 1;
    if (e < 15) PROJ_STAGE((e + 1) * 64, bi ^ 1);
    const unsigned short* is = in_s[bi];
    #pragma unroll
    for (int kk = 0; kk < 2; ++kk) {
      const int g0 = kk * 4 + quad;
      bf16x8 a0 = frag(is, wv * 32 + l15, g0);
      bf16x8 a1 = frag(is, wv * 32 + 16 + l15, g0);
      #pragma unroll
      for (int x = 0; x < 3; ++x) {
        const unsigned short* ws = w_s[bi][x];
        #pragma unroll
        for (int nb = 0; nb < 4; ++nb) {
          bf16x8 bfr = frag(ws, nb * 16 + l15, g0);
          acc[x][0][nb] = __builtin_amdgcn_mfma_f32_16x16x32_bf16(a0, bfr, acc[x][0][nb], 0, 0, 0);
          acc[x][1][nb] = __builtin_amdgcn_mfma_f32_16x16x32_bf16(a1, bfr, acc[x][1][nb], 0, 0, 0);
        }
      }
    }
    __syncthreads();
  }
#undef PROJ_STAGE

  const size_t obase = (size_t)(b * H_ + h) * T_;
  unsigned short* outs[3] = { qo, ko, vo };
  const float* biasp[3] = { qb, kb, vb };
  #pragma unroll
  for (int x = 0; x < 3; ++x) {
    #pragma unroll
    for (int nb = 0; nb < 4; ++nb) {
      const int d = nb * 16 + l15;
      const float bvv = biasp[x][h * D_ + d];
      #pragma unroll
      for (int s = 0; s < 2; ++s)
        #pragma unroll
        for (int r = 0; r < 4; ++r) {
          const int t = t0 + wv * 32 + s * 16 + quad * 4 + r;
          outs[x][(obase + t) * D_ + d] = f2bf(acc[x][s][nb][r] + bvv);
        }
    }
  }
}

// ---------------------------------------------------------------------------
// Column softmax sums + V pre-scale/transpose. grid (16, H, B) = 512 blocks.
// Block owns paired s-tiles (x, 31-x): uniform work. K-frags reg-resident;
// Q double-buffered DMA. Epilogue: vt[bh][d][t] = v[bh][t][d] / l[t].
// ---------------------------------------------------------------------------
__global__ __launch_bounds__(256) void stats_kernel(
    const unsigned short* __restrict__ q, const unsigned short* __restrict__ k,
    const unsigned short* __restrict__ v, unsigned short* __restrict__ vt)
{
  __shared__ __align__(16) unsigned short k_s[2][64 * 64];
  __shared__ __align__(16) unsigned short q_s[2][64 * 64];
  __shared__ float red[4][2][64];
  __shared__ float rl_sh[2][64];
  const int tid = threadIdx.x;
  const int lane = tid & 63, wv = tid >> 6;
  const int l15 = lane & 15, quad = lane >> 4;
  const int x = blockIdx.x;
  const int bh = blockIdx.z * H_ + blockIdx.y;
  const int sa = x, sb = 31 - x;
  const int s0a = sa * 64, s0b = sb * 64;

  #pragma unroll
  for (int j = 0; j < 4; ++j) {                       // stage both K tiles
    const int idx = wv * 4 + j;                       // 0..15
    const int tl = idx >> 3, br = (idx & 7) * 8;
    dma8(k + ((size_t)(bh * T_ + (tl ? s0b : s0a) + br)) * 64, 64,
         &k_s[tl][br * 64], lane);
  }
  #pragma unroll
  for (int p = 0; p < 2; ++p) {                       // stage Q tile tt=sa
    const int br = wv * 16 + p * 8;
    dma8(q + ((size_t)(bh * T_ + s0a + br)) * 64, 64, &q_s[0][br * 64], lane);
  }
  __syncthreads();

  bf16x8 kf[2][4][2];                                 // reg-resident K frags
  #pragma unroll
  for (int tl = 0; tl < 2; ++tl)
    #pragma unroll
    for (int nb = 0; nb < 4; ++nb)
      #pragma unroll
      for (int kk = 0; kk < 2; ++kk)
        kf[tl][nb][kk] = frag(k_s[tl], nb * 16 + l15, kk * 4 + quad);

  float lsum[2][4];
  #pragma unroll
  for (int tl = 0; tl < 2; ++tl)
    #pragma unroll
    for (int nb = 0; nb < 4; ++nb) lsum[tl][nb] = 0.f;

  for (int tt = sa; tt < NT_; ++tt) {
    const int bi = (tt - sa) & 1;
    if (tt < NT_ - 1) {
      #pragma unroll
      for (int p = 0; p < 2; ++p) {
        const int br = wv * 16 + p * 8;
        dma8(q + ((size_t)(bh * T_ + (tt + 1) * 64 + br)) * 64, 64,
             &q_s[bi ^ 1][br * 64], lane);
      }
    }
    bf16x8 a0 = frag(q_s[bi], wv * 16 + l15, quad);
    bf16x8 a1 = frag(q_s[bi], wv * 16 + l15, 4 + quad);
    const int tbase = tt * 64 + wv * 16 + quad * 4;
    {                                                  // tile a, always active
      f32x4 sacc[4];
      #pragma unroll
      for (int nb = 0; nb < 4; ++nb) sacc[nb] = (f32x4){0.f, 0.f, 0.f, 0.f};
      #pragma unroll
      for (int nb = 0; nb < 4; ++nb) {
        sacc[nb] = __builtin_amdgcn_mfma_f32_16x16x32_bf16(a0, kf[0][nb][0], sacc[nb], 0, 0, 0);
        sacc[nb] = __builtin_amdgcn_mfma_f32_16x16x32_bf16(a1, kf[0][nb][1], sacc[nb], 0, 0, 0);
      }
      #pragma unroll
      for (int nb = 0; nb < 4; ++nb) {
        const int s = s0a + nb * 16 + l15;
        #pragma unroll
        for (int r = 0; r < 4; ++r)
          lsum[0][nb] += (tbase + r >= s) ? __expf(sacc[nb][r] * 0.125f) : 0.f;
      }
    }
    if (tt >= sb) {                                    // tile b
      f32x4 sacc[4];
      #pragma unroll
      for (int nb = 0; nb < 4; ++nb) sacc[nb] = (f32x4){0.f, 0.f, 0.f, 0.f};
      #pragma unroll
      for (int nb = 0; nb < 4; ++nb) {
        sacc[nb] = __builtin_amdgcn_mfma_f32_16x16x32_bf16(a0, kf[1][nb][0], sacc[nb], 0, 0, 0);
        sacc[nb] = __builtin_amdgcn_mfma_f32_16x16x32_bf16(a1, kf[1][nb][1], sacc[nb], 0, 0, 0);
      }
      #pragma unroll
      for (int nb = 0; nb < 4; ++nb) {
        const int s = s0b + nb * 16 + l15;
        #pragma unroll
        for (int r = 0; r < 4; ++r)
          lsum[1][nb] += (tbase + r >= s) ? __expf(sacc[nb][r] * 0.125f) : 0.f;
      }
    }
    __syncthreads();
  }

  #pragma unroll
  for (int tl = 0; tl < 2; ++tl)
    #pragma unroll
    for (int nb = 0; nb < 4; ++nb) {
      lsum[tl][nb] += __shfl_xor(lsum[tl][nb], 16);
      lsum[tl][nb] += __shfl_xor(lsum[tl][nb], 32);
    }
  if (lane < 16) {
    #pragma unroll
    for (int tl = 0; tl < 2; ++tl)
      #pragma unroll
      for (int nb = 0; nb < 4; ++nb) red[wv][tl][nb * 16 + lane] = lsum[tl][nb];
  }
  __syncthreads();
  if (tid < 128) {
    const int tl = tid >> 6, sL = tid & 63;
    const float L = red[0][tl][sL] + red[1][tl][sL] + red[2][tl][sL] + red[3][tl][sL];
    rl_sh[tl][sL] = 1.0f / L;
  }
  __syncthreads();
  // vt[bh][d][t] = v[bh][t][d] * rl[t]
  #pragma unroll
  for (int tl = 0; tl < 2; ++tl) {
    const int s0 = tl ? s0b : s0a;
    const int sI = tid >> 2, c = (tid & 3) * 16;
    const unsigned short* gv = v + ((size_t)(bh * T_ + s0 + sI)) * 64 + c;
    bf16x8 v0 = *(const bf16x8*)gv;
    bf16x8 v1 = *(const bf16x8*)(gv + 8);
    const float r = rl_sh[tl][sI];
    #pragma unroll
    for (int j = 0; j < 8; ++j)
      vt[((size_t)(bh * D_ + c + j)) * T_ + s0 + sI] = f2bf(bf2f((unsigned short)v0[j]) * r);
    #pragma unroll
    for (int j = 0; j < 8; ++j)
      vt[((size_t)(bh * D_ + c + 8 + j)) * T_ + s0 + sI] = f2bf(bf2f((unsigned short)v1[j]) * r);
  }
}

// ---------------------------------------------------------------------------
// Output. grid (16, H, B) = 512 blocks. Block owns paired t-tiles (x, 31-x).
// Computes S^T = K.Q^T (C-layout gives 4 consecutive s per lane -> b64 U
// writes, wave-private rows), then O += U.Vt via MFMA. K/Vt double-buffered.
// ---------------------------------------------------------------------------
__global__ __launch_bounds__(256) void out_kernel(
    const unsigned short* __restrict__ q, const unsigned short* __restrict__ k,
    const unsigned short* __restrict__ vt, float* __restrict__ out)
{
  __shared__ __align__(16) unsigned short q_s[2][64 * 64];
  __shared__ __align__(16) unsigned short k_s[2][64 * 64];
  __shared__ __align__(16) unsigned short vt_s[2][64 * 64];
  __shared__ __align__(16) unsigned short u_s[2][64 * 72];   // [tile][t][s], stride 72
  const int tid = threadIdx.x;
  const int lane = tid & 63, wv = tid >> 6;
  const int l15 = lane & 15, quad = lane >> 4;
  const int xp = blockIdx.x;
  const int bh = blockIdx.z * H_ + blockIdx.y;
  const int ja = xp, jb = 31 - xp;
  const int t0a = ja * 64, t0b = jb * 64;

  #pragma unroll
  for (int j = 0; j < 4; ++j) {                       // stage both Q tiles
    const int idx = wv * 4 + j;
    const int tl = idx >> 3, br = (idx & 7) * 8;
    dma8(q + ((size_t)(bh * T_ + (tl ? t0b : t0a) + br)) * 64, 64,
         &q_s[tl][br * 64], lane);
  }
  #pragma unroll
  for (int p = 0; p < 2; ++p) {                       // stage K/Vt tile 0
    const int br = wv * 16 + p * 8;
    dma8(k + ((size_t)(bh * T_ + br)) * 64, 64, &k_s[0][br * 64], lane);
    dma8(vt + ((size_t)(bh * D_ + br)) * T_, T_, &vt_s[0][br * 64], lane);
  }
  __syncthreads();

  bf16x8 qf[2][2];                                    // reg-resident Q frags
  #pragma unroll
  for (int tl = 0; tl < 2; ++tl)
    #pragma unroll
    for (int kk = 0; kk < 2; ++kk)
      qf[tl][kk] = frag(q_s[tl], wv * 16 + l15, kk * 4 + quad);
  __syncthreads();                                    // preload done before u_s use

  f32x4 oacc[2][4];
  #pragma unroll
  for (int tl = 0; tl < 2; ++tl)
    #pragma unroll
    for (int nb = 0; nb < 4; ++nb) oacc[tl][nb] = (f32x4){0.f, 0.f, 0.f, 0.f};

  for (int st = 0; st <= jb; ++st) {
    const int bi = st & 1;
    if (st < jb) {
      const int s1 = (st + 1) * 64;
      #pragma unroll
      for (int p = 0; p < 2; ++p) {
        const int br = wv * 16 + p * 8;
        dma8(k + ((size_t)(bh * T_ + s1 + br)) * 64, 64, &k_s[bi ^ 1][br * 64], lane);
        dma8(vt + ((size_t)(bh * D_ + br)) * T_ + s1, T_, &vt_s[bi ^ 1][br * 64], lane);
      }
    }
    const int s0 = st * 64;
    const unsigned short* ks = k_s[bi];
    const unsigned short* vs = vt_s[bi];
    bf16x8 kfA[4][2];                                 // A-frags (K rows s), shared by tiles
    #pragma unroll
    for (int mb = 0; mb < 4; ++mb)
      #pragma unroll
      for (int kk = 0; kk < 2; ++kk)
        kfA[mb][kk] = frag(ks, mb * 16 + l15, kk * 4 + quad);

    #pragma unroll
    for (int ti = 0; ti < 2; ++ti) {
      if (ti == 0 && st > ja) continue;               // tile a finished
      const int t0 = ti ? t0b : t0a;
      const int tcol = t0 + wv * 16 + l15;            // this lane's t (n-dim)
      f32x4 sacc[4];
      #pragma unroll
      for (int mb = 0; mb < 4; ++mb) sacc[mb] = (f32x4){0.f, 0.f, 0.f, 0.f};
      #pragma unroll
      for (int mb = 0; mb < 4; ++mb) {
        sacc[mb] = __builtin_amdgcn_mfma_f32_16x16x32_bf16(kfA[mb][0], qf[ti][0], sacc[mb], 0, 0, 0);
        sacc[mb] = __builtin_amdgcn_mfma_f32_16x16x32_bf16(kfA[mb][1], qf[ti][1], sacc[mb], 0, 0, 0);
      }
      // U = exp(S*scale) masked, bf16, wave-private row t = wv*16+l15
      unsigned short* urow = &u_s[ti][(wv * 16 + l15) * 72];
      #pragma unroll
      for (int mb = 0; mb < 4; ++mb) {
        const int sbase = s0 + mb * 16 + quad * 4;
        float uu[4];
        #pragma unroll
        for (int r = 0; r < 4; ++r)
          uu[r] = (tcol >= sbase + r) ? __expf(sacc[mb][r] * 0.125f) : 0.f;
        *(uint2*)(urow + mb * 16 + quad * 4) =
            make_uint2(pk2bf(uu[0], uu[1]), pk2bf(uu[2], uu[3]));
      }
      // O += U @ Vt' (A = own U row, B = vt rows d) — same-wave LDS dep, no barrier
      #pragma unroll
      for (int kk = 0; kk < 2; ++kk) {
        bf16x8 ua = *(const bf16x8*)(&u_s[ti][(wv * 16 + l15) * 72 + kk * 32 + quad * 8]);
        #pragma unroll
        for (int nb = 0; nb < 4; ++nb)
          oacc[ti][nb] = __builtin_amdgcn_mfma_f32_16x16x32_bf16(
              ua, frag(vs, nb * 16 + l15, kk * 4 + quad), oacc[ti][nb], 0, 0, 0);
      }
    }
    __syncthreads();
  }
  // write (B, T, H*D) fp32
  #pragma unroll
  for (int ti = 0; ti < 2; ++ti) {
    const int t0 = ti ? t0b : t0a;
    #pragma unroll
    for (int nb = 0; nb < 4; ++nb) {
      const int d = nb * 16 + l15;
      #pragma unroll
      for (int r = 0; r < 4; ++r) {
        const int t = t0 + wv * 16 + quad * 4 + r;
        out[((size_t)(blockIdx.z * T_ + t)) * (H_ * D_) + blockIdx.y * D_ + d] = oacc[ti][nb][r];
      }
    }
  }
}

extern "C" void kernel_launch(void* const* d_in, const int* in_sizes, int n_in,
                              void* d_out, int out_size, void* d_ws, size_t ws_size,
                              hipStream_t stream) {
  const float* in = (const float*)d_in[0];
  const float* kw = (const float*)d_in[1];
  const float* kb = (const float*)d_in[2];
  const float* qw = (const float*)d_in[3];
  const float* qb = (const float*)d_in[4];
  const float* vw = (const float*)d_in[5];
  const float* vb = (const float*)d_in[6];
  float* out = (float*)d_out;

  // ws (bf16): in16 | qwt|kwt|vwt (H,D,E) | q16|k16|v16 (B,H,T,D) | vt (B,H,D,T)
  unsigned short* p = (unsigned short*)d_ws;
  const size_t inz = (size_t)B_ * T_ * E_;        // 4,194,304
  const size_t wz  = (size_t)H_ * D_ * E_;        // 1,048,576
  const size_t qz  = (size_t)B_ * H_ * T_ * D_;   // 4,194,304
  unsigned short* in16 = p;            p += inz;
  unsigned short* qwt  = p;            p += wz;
  unsigned short* kwt  = p;            p += wz;
  unsigned short* vwt  = p;            p += wz;
  unsigned short* q16  = p;            p += qz;
  unsigned short* k16  = p;            p += qz;
  unsigned short* v16  = p;            p += qz;
  unsigned short* vtb  = p;            p += qz;

  dim3 blk(256);
  inpack_kernel<<<dim3(inz / 2048), blk, 0, stream>>>(in, in16);
  wpack_kernel <<<dim3(E_ / 64, H_, 3), blk, 0, stream>>>(qw, kw, vw, qwt, kwt, vwt);
  proj_kernel  <<<dim3(T_ / 128, H_, B_), blk, 0, stream>>>(in16, qwt, kwt, vwt,
                                                            qb, kb, vb, q16, k16, v16);
  stats_kernel <<<dim3(16, H_, B_), blk, 0, stream>>>(q16, k16, v16, vtb);
  out_kernel   <<<dim3(16, H_, B_), blk, 0, stream>>>(q16, k16, vtb, out);
}